// Round 1
// baseline (570.847 us; speedup 1.0000x reference)
//
#include <hip/hip_runtime.h>

// ScaledDotProductAttention: B=4,S=2048,H=16,D=64, scores/8, mask->1e-20 (~0), softmax, PV.
// Flash-style, bf16 MFMA 16x16x32, S^T layout (A=K,B=Q^T) so mask loads are int4-vectorized.
// PV uses custom summation-index ordering so P^T B-frag is lane-local (no transposes).

typedef __attribute__((ext_vector_type(8))) short short8;
typedef __attribute__((ext_vector_type(4))) float f32x4;
typedef __attribute__((ext_vector_type(4))) int   i32x4;

#define MFMA(a, b, c) __builtin_amdgcn_mfma_f32_16x16x32_bf16((a), (b), (c), 0, 0, 0)

static __device__ __forceinline__ short f2bf(float f) {
    __bf16 h = (__bf16)f;
    return __builtin_bit_cast(short, h);
}

__global__ __launch_bounds__(256, 2)
void attn_fwd(const float* __restrict__ Q, const float* __restrict__ K,
              const float* __restrict__ V, const int* __restrict__ M,
              float* __restrict__ O)
{
    constexpr int S = 2048;
    constexpr int HD = 1024;   // H*D
    constexpr int Dd = 64;
    const float QSCALE = 0.125f * 1.44269504088896340736f; // (1/sqrt(64)) * log2(e): work in exp2 domain

    // XCD-bijective swizzle: 512 blocks, 8 XCDs, 64 blocks/XCD chunk.
    int orig = blockIdx.x;
    int wg   = (orig & 7) * 64 + (orig >> 3);
    int bh   = wg >> 3;    // 0..63  (b*16 + h)
    int qb   = wg & 7;     // 0..7
    int b    = bh >> 4;
    int h    = bh & 15;

    int lane = threadIdx.x & 63;
    int wave = threadIdx.x >> 6;
    int g    = lane >> 4;     // 16-lane group 0..3
    int c    = lane & 15;     // column within group

    int q0 = qb * 256 + wave * 64;   // this wave's q base (64 rows)

    const float* qbase = Q + (long)(b * S) * HD + h * Dd;
    const float* kbase = K + (long)(b * S) * HD + h * Dd;
    const float* vbase = V + (long)(b * S) * HD + h * Dd;
    const int*   mbase = M + ((long)bh << 22);          // bh * S * S
    float*       obase = O + (long)(b * S) * HD + h * Dd;

    // ---- Q fragments (B-operand of S^T mfma): lane holds Q[q0+qt*16+c][hf*32+g*8 .. +7], scaled
    short8 qf[4][2];
#pragma unroll
    for (int qt = 0; qt < 4; ++qt) {
        const float* qr = qbase + (long)(q0 + qt * 16 + c) * HD;
#pragma unroll
        for (int hf = 0; hf < 2; ++hf) {
            f32x4 x0 = *(const f32x4*)(qr + hf * 32 + g * 8);
            f32x4 x1 = *(const f32x4*)(qr + hf * 32 + g * 8 + 4);
            short8 t;
            t[0] = f2bf(x0[0] * QSCALE); t[1] = f2bf(x0[1] * QSCALE);
            t[2] = f2bf(x0[2] * QSCALE); t[3] = f2bf(x0[3] * QSCALE);
            t[4] = f2bf(x1[0] * QSCALE); t[5] = f2bf(x1[1] * QSCALE);
            t[6] = f2bf(x1[2] * QSCALE); t[7] = f2bf(x1[3] * QSCALE);
            qf[qt][hf] = t;
        }
    }

    f32x4 acc[4][4];   // [qt][dt] : O^T accum, lane holds (d = dt*16 + g*4 + r, q = qt*16 + c)
#pragma unroll
    for (int qt = 0; qt < 4; ++qt)
#pragma unroll
        for (int dt = 0; dt < 4; ++dt) acc[qt][dt] = (f32x4){0.f, 0.f, 0.f, 0.f};
    float mrow[4] = {-INFINITY, -INFINITY, -INFINITY, -INFINITY};
    float lrow[4] = {0.f, 0.f, 0.f, 0.f};

#pragma unroll 1
    for (int step = 0; step < S / 64; ++step) {
        int kv0 = step * 64;

        // ---- K fragments (A-operand of S^T): lane holds K[kv0+kt*16+c][hf*32+g*8 .. +7]
        short8 kf[4][2];
#pragma unroll
        for (int kt = 0; kt < 4; ++kt) {
            const float* kr = kbase + (long)(kv0 + kt * 16 + c) * HD;
#pragma unroll
            for (int hf = 0; hf < 2; ++hf) {
                f32x4 x0 = *(const f32x4*)(kr + hf * 32 + g * 8);
                f32x4 x1 = *(const f32x4*)(kr + hf * 32 + g * 8 + 4);
                short8 t;
                t[0] = f2bf(x0[0]); t[1] = f2bf(x0[1]); t[2] = f2bf(x0[2]); t[3] = f2bf(x0[3]);
                t[4] = f2bf(x1[0]); t[5] = f2bf(x1[1]); t[6] = f2bf(x1[2]); t[7] = f2bf(x1[3]);
                kf[kt][hf] = t;
            }
        }

        // ---- V fragments (A-operand of PV, O^T = V^T * P^T) with custom kappa order:
        // element i: kv = kv0 + hf*32 + (i<4 ? g*4+i : 16 + g*4 + (i-4)), d = dt*16 + c
        short8 vf[4][2];
#pragma unroll
        for (int hf = 0; hf < 2; ++hf) {
            const float* vr[8];
#pragma unroll
            for (int i = 0; i < 4; ++i) {
                vr[i]     = vbase + (long)(kv0 + hf * 32 + g * 4 + i) * HD + c;
                vr[4 + i] = vbase + (long)(kv0 + hf * 32 + 16 + g * 4 + i) * HD + c;
            }
#pragma unroll
            for (int dt = 0; dt < 4; ++dt) {
                short8 t;
#pragma unroll
                for (int i = 0; i < 8; ++i) t[i] = f2bf(vr[i][dt * 16]);
                vf[dt][hf] = t;
            }
        }

        // ---- per q-tile: S^T mfma -> mask -> online softmax -> PV mfma
#pragma unroll
        for (int qt = 0; qt < 4; ++qt) {
            f32x4 st[4];
#pragma unroll
            for (int kt = 0; kt < 4; ++kt) {
                f32x4 z = (f32x4){0.f, 0.f, 0.f, 0.f};
                z = MFMA(kf[kt][0], qf[qt][0], z);
                z = MFMA(kf[kt][1], qf[qt][1], z);
                st[kt] = z;   // (kv = kv0+kt*16+g*4+r, q = q0+qt*16+c), log2e-scaled scores
            }

            // mask: int4 per (qt,kt) — 4 consecutive kv for this lane's q row
            const int* mrp = mbase + ((long)(q0 + qt * 16 + c) << 11) + kv0 + g * 4;
            float p[4][4];
            float mx = -INFINITY;
#pragma unroll
            for (int kt = 0; kt < 4; ++kt) {
                i32x4 mk = *(const i32x4*)(mrp + kt * 16);
#pragma unroll
                for (int r = 0; r < 4; ++r) {
                    float val = (mk[r] != 0) ? st[kt][r] : 0.0f;  // 1e-20 ~ 0
                    p[kt][r] = val;
                    mx = fmaxf(mx, val);
                }
            }
            mx = fmaxf(mx, __shfl_xor(mx, 16));
            mx = fmaxf(mx, __shfl_xor(mx, 32));
            float mnew  = fmaxf(mrow[qt], mx);
            float alpha = exp2f(mrow[qt] - mnew);
            mrow[qt] = mnew;

            float sum = 0.f;
#pragma unroll
            for (int kt = 0; kt < 4; ++kt)
#pragma unroll
                for (int r = 0; r < 4; ++r) {
                    float e = exp2f(p[kt][r] - mnew);
                    p[kt][r] = e;
                    sum += e;
                }
            sum += __shfl_xor(sum, 16);
            sum += __shfl_xor(sum, 32);
            lrow[qt] = lrow[qt] * alpha + sum;

#pragma unroll
            for (int dt = 0; dt < 4; ++dt) acc[qt][dt] = acc[qt][dt] * alpha;

            // P^T B-frags, lane-local thanks to kappa ordering (matches vf)
            short8 pb0, pb1;
            pb0[0] = f2bf(p[0][0]); pb0[1] = f2bf(p[0][1]); pb0[2] = f2bf(p[0][2]); pb0[3] = f2bf(p[0][3]);
            pb0[4] = f2bf(p[1][0]); pb0[5] = f2bf(p[1][1]); pb0[6] = f2bf(p[1][2]); pb0[7] = f2bf(p[1][3]);
            pb1[0] = f2bf(p[2][0]); pb1[1] = f2bf(p[2][1]); pb1[2] = f2bf(p[2][2]); pb1[3] = f2bf(p[2][3]);
            pb1[4] = f2bf(p[3][0]); pb1[5] = f2bf(p[3][1]); pb1[6] = f2bf(p[3][2]); pb1[7] = f2bf(p[3][3]);

#pragma unroll
            for (int dt = 0; dt < 4; ++dt) {
                acc[qt][dt] = MFMA(vf[dt][0], pb0, acc[qt][dt]);
                acc[qt][dt] = MFMA(vf[dt][1], pb1, acc[qt][dt]);
            }
        }
    }

    // ---- epilogue: divide by l, store O[q][d] (f32, float4 per lane)
#pragma unroll
    for (int qt = 0; qt < 4; ++qt) {
        float inv = 1.0f / lrow[qt];
        float* orow = obase + (long)(q0 + qt * 16 + c) * HD;
#pragma unroll
        for (int dt = 0; dt < 4; ++dt) {
            f32x4 o = acc[qt][dt] * inv;
            *(f32x4*)(orow + dt * 16 + g * 4) = o;
        }
    }
}

extern "C" void kernel_launch(void* const* d_in, const int* in_sizes, int n_in,
                              void* d_out, int out_size, void* d_ws, size_t ws_size,
                              hipStream_t stream) {
    const float* q = (const float*)d_in[0];
    const float* k = (const float*)d_in[1];
    const float* v = (const float*)d_in[2];
    const int*   m = (const int*)d_in[3];
    float* out = (float*)d_out;
    attn_fwd<<<dim3(512), dim3(256), 0, stream>>>(q, k, v, m, out);
}

// Round 2
// 311.067 us; speedup vs baseline: 1.8351x; 1.8351x over previous
//
#include <hip/hip_runtime.h>

// B=4,S=2048,H=16,D=64. scores/8, mask->1e-20(~0), softmax, PV.
// Round 2: prepack K/V -> bf16 MFMA fragments in d_ws (kills per-step cvt + scalar
// gathers, halves K/V bytes); nontemporal mask stream (preserve L2 for K/V);
// no-max softmax (masked = exp2(0) = 1 exactly, matches ref 1e-20 semantics).

typedef __attribute__((ext_vector_type(8))) short short8;
typedef __attribute__((ext_vector_type(4))) float f32x4;
typedef __attribute__((ext_vector_type(4))) int   i32x4;

#define MFMA(a, b, c) __builtin_amdgcn_mfma_f32_16x16x32_bf16((a), (b), (c), 0, 0, 0)

static __device__ __forceinline__ short f2bf(float f) {
    __bf16 h = (__bf16)f;
    return __builtin_bit_cast(short, h);
}

constexpr int S_ = 2048, HD_ = 1024, STEPS_ = 32;
constexpr long KP_ELEMS = 64L * 32 * 4 * 2 * 64 * 8;   // 8,388,608 bf16 per tensor

// ---- prepack K: Kp[t*8..+7] = bf16 K-fragment, t = bh*16384+step*512+kt*128+hf*64+lane
__global__ __launch_bounds__(256) void prepack_k(const float* __restrict__ K, short* __restrict__ Kp) {
    int t = blockIdx.x * 256 + threadIdx.x;
    int lane = t & 63, hf = (t >> 6) & 1, kt = (t >> 7) & 3, step = (t >> 9) & 31, bh = t >> 14;
    int g = lane >> 4, c = lane & 15, b = bh >> 4, h = bh & 15;
    int row = step * 64 + kt * 16 + c;
    const float* src = K + (long)(b * S_ + row) * HD_ + h * 64 + hf * 32 + g * 8;
    f32x4 x0 = *(const f32x4*)src, x1 = *(const f32x4*)(src + 4);
    short8 o;
    o[0] = f2bf(x0[0]); o[1] = f2bf(x0[1]); o[2] = f2bf(x0[2]); o[3] = f2bf(x0[3]);
    o[4] = f2bf(x1[0]); o[5] = f2bf(x1[1]); o[6] = f2bf(x1[2]); o[7] = f2bf(x1[3]);
    *(short8*)(Kp + (long)t * 8) = o;
}

// ---- prepack V^T with kappa-ordering: element i of lane(g,c), tile(dt,hf):
//      row = step*64 + hf*32 + (i<4 ? g*4+i : 16+g*4+(i-4)), col = dt*16+c
__global__ __launch_bounds__(256) void prepack_v(const float* __restrict__ V, short* __restrict__ Vp) {
    int t = blockIdx.x * 256 + threadIdx.x;
    int lane = t & 63, hf = (t >> 6) & 1, dt = (t >> 7) & 3, step = (t >> 9) & 31, bh = t >> 14;
    int g = lane >> 4, c = lane & 15, b = bh >> 4, h = bh & 15;
    int col = dt * 16 + c, row0 = step * 64 + hf * 32;
    const float* vb = V + (long)(b * S_) * HD_ + h * 64 + col;
    short8 o;
#pragma unroll
    for (int i = 0; i < 8; ++i) {
        int row = row0 + ((i < 4) ? g * 4 + i : 16 + g * 4 + (i - 4));
        o[i] = f2bf(vb[(long)row * HD_]);
    }
    *(short8*)(Vp + (long)t * 8) = o;
}

// ---- hot kernel
__global__ __launch_bounds__(256, 2)
void attn_fwd2(const float* __restrict__ Q, const short* __restrict__ Kp,
               const short* __restrict__ Vp, const int* __restrict__ M,
               float* __restrict__ O)
{
    const float QSCALE = 0.125f * 1.44269504088896340736f;  // 1/sqrt(64) * log2(e)

    int orig = blockIdx.x;
    int wg   = (orig & 7) * 64 + (orig >> 3);   // XCD-bijective swizzle (512 % 8 == 0)
    int bh   = wg >> 3, qb = wg & 7;
    int b    = bh >> 4, h = bh & 15;

    int lane = threadIdx.x & 63, wave = threadIdx.x >> 6;
    int g = lane >> 4, c = lane & 15;
    int q0 = qb * 256 + wave * 64;

    const float* qbase = Q + (long)(b * S_) * HD_ + h * 64;
    const int*   mbase = M + ((long)bh << 22);
    float*       obase = O + (long)(b * S_) * HD_ + h * 64;
    const short* kpb   = Kp + (long)bh * STEPS_ * 4096;
    const short* vpb   = Vp + (long)bh * STEPS_ * 4096;

    // Q fragments (B-operand): lane holds Q[q0+qt*16+c][hf*32+g*8 ..+7] * QSCALE
    short8 qf[4][2];
#pragma unroll
    for (int qt = 0; qt < 4; ++qt) {
        const float* qr = qbase + (long)(q0 + qt * 16 + c) * HD_;
#pragma unroll
        for (int hf = 0; hf < 2; ++hf) {
            f32x4 x0 = *(const f32x4*)(qr + hf * 32 + g * 8);
            f32x4 x1 = *(const f32x4*)(qr + hf * 32 + g * 8 + 4);
            short8 t;
            t[0] = f2bf(x0[0] * QSCALE); t[1] = f2bf(x0[1] * QSCALE);
            t[2] = f2bf(x0[2] * QSCALE); t[3] = f2bf(x0[3] * QSCALE);
            t[4] = f2bf(x1[0] * QSCALE); t[5] = f2bf(x1[1] * QSCALE);
            t[6] = f2bf(x1[2] * QSCALE); t[7] = f2bf(x1[3] * QSCALE);
            qf[qt][hf] = t;
        }
    }

    f32x4 acc[4][4];
#pragma unroll
    for (int qt = 0; qt < 4; ++qt)
#pragma unroll
        for (int dt = 0; dt < 4; ++dt) acc[qt][dt] = (f32x4){0.f, 0.f, 0.f, 0.f};
    float lsum[4] = {0.f, 0.f, 0.f, 0.f};

    // prologue: mask for (step 0, qt 0)
    i32x4 mk[4];
    {
        const int* mp = mbase + ((long)(q0 + c) << 11) + g * 4;
#pragma unroll
        for (int kt = 0; kt < 4; ++kt)
            mk[kt] = __builtin_nontemporal_load((const i32x4*)(mp + kt * 16));
    }

#pragma unroll 1
    for (int step = 0; step < STEPS_; ++step) {
        const short* kp = kpb + (long)step * 4096;
        const short* vp = vpb + (long)step * 4096;
        short8 kf[4][2], vf[4][2];
#pragma unroll
        for (int kt = 0; kt < 4; ++kt)
#pragma unroll
            for (int hf = 0; hf < 2; ++hf) {
                kf[kt][hf] = *(const short8*)(kp + ((kt * 2 + hf) * 64 + lane) * 8);
                vf[kt][hf] = *(const short8*)(vp + ((kt * 2 + hf) * 64 + lane) * 8);
            }

#pragma unroll
        for (int qt = 0; qt < 4; ++qt) {
            // prefetch next (step,qt)'s mask (last iter: harmless reload of same)
            int nstep = (qt < 3) ? step : ((step < STEPS_ - 1) ? step + 1 : step);
            int nqt   = (qt < 3) ? qt + 1 : ((step < STEPS_ - 1) ? 0 : qt);
            i32x4 mkn[4];
            const int* mpn = mbase + ((long)(q0 + nqt * 16 + c) << 11) + nstep * 64 + g * 4;
#pragma unroll
            for (int kt = 0; kt < 4; ++kt)
                mkn[kt] = __builtin_nontemporal_load((const i32x4*)(mpn + kt * 16));

            f32x4 st[4];
#pragma unroll
            for (int kt = 0; kt < 4; ++kt) {
                f32x4 z = (f32x4){0.f, 0.f, 0.f, 0.f};
                z = MFMA(kf[kt][0], qf[qt][0], z);
                z = MFMA(kf[kt][1], qf[qt][1], z);
                st[kt] = z;   // kv = step*64+kt*16+g*4+r, q = q0+qt*16+c (log2e-scaled)
            }

            float p[4][4];
            float s = 0.f;
#pragma unroll
            for (int kt = 0; kt < 4; ++kt)
#pragma unroll
                for (int r = 0; r < 4; ++r) {
                    float val = (mk[kt][r] != 0) ? st[kt][r] : 0.0f;  // masked -> exp2(0)=1
                    float e = exp2f(val);
                    p[kt][r] = e;
                    s += e;
                }
            lsum[qt] += s;

            short8 pb0, pb1;
            pb0[0] = f2bf(p[0][0]); pb0[1] = f2bf(p[0][1]); pb0[2] = f2bf(p[0][2]); pb0[3] = f2bf(p[0][3]);
            pb0[4] = f2bf(p[1][0]); pb0[5] = f2bf(p[1][1]); pb0[6] = f2bf(p[1][2]); pb0[7] = f2bf(p[1][3]);
            pb1[0] = f2bf(p[2][0]); pb1[1] = f2bf(p[2][1]); pb1[2] = f2bf(p[2][2]); pb1[3] = f2bf(p[2][3]);
            pb1[4] = f2bf(p[3][0]); pb1[5] = f2bf(p[3][1]); pb1[6] = f2bf(p[3][2]); pb1[7] = f2bf(p[3][3]);

#pragma unroll
            for (int dt = 0; dt < 4; ++dt) {
                acc[qt][dt] = MFMA(vf[dt][0], pb0, acc[qt][dt]);
                acc[qt][dt] = MFMA(vf[dt][1], pb1, acc[qt][dt]);
            }

#pragma unroll
            for (int kt = 0; kt < 4; ++kt) mk[kt] = mkn[kt];
        }
    }

    // epilogue: reduce row sums across g-groups, normalize, store
#pragma unroll
    for (int qt = 0; qt < 4; ++qt) {
        float t0 = lsum[qt];
        t0 += __shfl_xor(t0, 16);
        t0 += __shfl_xor(t0, 32);
        float inv = 1.0f / t0;
        float* orow = obase + (long)(q0 + qt * 16 + c) * HD_;
#pragma unroll
        for (int dt = 0; dt < 4; ++dt) {
            f32x4 o = acc[qt][dt] * inv;
            __builtin_nontemporal_store(o, (f32x4*)(orow + dt * 16 + g * 4));
        }
    }
}

// ---- round-1 fallback (used only if ws_size is too small) ----
__global__ __launch_bounds__(256, 2)
void attn_fwd(const float* __restrict__ Q, const float* __restrict__ K,
              const float* __restrict__ V, const int* __restrict__ M,
              float* __restrict__ O)
{
    const float QSCALE = 0.125f * 1.44269504088896340736f;
    int orig = blockIdx.x;
    int wg   = (orig & 7) * 64 + (orig >> 3);
    int bh   = wg >> 3, qb = wg & 7;
    int b    = bh >> 4, h = bh & 15;
    int lane = threadIdx.x & 63, wave = threadIdx.x >> 6;
    int g = lane >> 4, c = lane & 15;
    int q0 = qb * 256 + wave * 64;

    const float* qbase = Q + (long)(b * S_) * HD_ + h * 64;
    const float* kbase = K + (long)(b * S_) * HD_ + h * 64;
    const float* vbase = V + (long)(b * S_) * HD_ + h * 64;
    const int*   mbase = M + ((long)bh << 22);
    float*       obase = O + (long)(b * S_) * HD_ + h * 64;

    short8 qf[4][2];
#pragma unroll
    for (int qt = 0; qt < 4; ++qt) {
        const float* qr = qbase + (long)(q0 + qt * 16 + c) * HD_;
#pragma unroll
        for (int hf = 0; hf < 2; ++hf) {
            f32x4 x0 = *(const f32x4*)(qr + hf * 32 + g * 8);
            f32x4 x1 = *(const f32x4*)(qr + hf * 32 + g * 8 + 4);
            short8 t;
            t[0] = f2bf(x0[0] * QSCALE); t[1] = f2bf(x0[1] * QSCALE);
            t[2] = f2bf(x0[2] * QSCALE); t[3] = f2bf(x0[3] * QSCALE);
            t[4] = f2bf(x1[0] * QSCALE); t[5] = f2bf(x1[1] * QSCALE);
            t[6] = f2bf(x1[2] * QSCALE); t[7] = f2bf(x1[3] * QSCALE);
            qf[qt][hf] = t;
        }
    }

    f32x4 acc[4][4];
#pragma unroll
    for (int qt = 0; qt < 4; ++qt)
#pragma unroll
        for (int dt = 0; dt < 4; ++dt) acc[qt][dt] = (f32x4){0.f, 0.f, 0.f, 0.f};
    float lsum[4] = {0.f, 0.f, 0.f, 0.f};

#pragma unroll 1
    for (int step = 0; step < STEPS_; ++step) {
        int kv0 = step * 64;
        short8 kf[4][2];
#pragma unroll
        for (int kt = 0; kt < 4; ++kt) {
            const float* kr = kbase + (long)(kv0 + kt * 16 + c) * HD_;
#pragma unroll
            for (int hf = 0; hf < 2; ++hf) {
                f32x4 x0 = *(const f32x4*)(kr + hf * 32 + g * 8);
                f32x4 x1 = *(const f32x4*)(kr + hf * 32 + g * 8 + 4);
                short8 t;
                t[0] = f2bf(x0[0]); t[1] = f2bf(x0[1]); t[2] = f2bf(x0[2]); t[3] = f2bf(x0[3]);
                t[4] = f2bf(x1[0]); t[5] = f2bf(x1[1]); t[6] = f2bf(x1[2]); t[7] = f2bf(x1[3]);
                kf[kt][hf] = t;
            }
        }
        short8 vf[4][2];
#pragma unroll
        for (int hf = 0; hf < 2; ++hf) {
            const float* vr[8];
#pragma unroll
            for (int i = 0; i < 4; ++i) {
                vr[i]     = vbase + (long)(kv0 + hf * 32 + g * 4 + i) * HD_ + c;
                vr[4 + i] = vbase + (long)(kv0 + hf * 32 + 16 + g * 4 + i) * HD_ + c;
            }
#pragma unroll
            for (int dt = 0; dt < 4; ++dt) {
                short8 t;
#pragma unroll
                for (int i = 0; i < 8; ++i) t[i] = f2bf(vr[i][dt * 16]);
                vf[dt][hf] = t;
            }
        }
#pragma unroll
        for (int qt = 0; qt < 4; ++qt) {
            f32x4 st[4];
#pragma unroll
            for (int kt = 0; kt < 4; ++kt) {
                f32x4 z = (f32x4){0.f, 0.f, 0.f, 0.f};
                z = MFMA(kf[kt][0], qf[qt][0], z);
                z = MFMA(kf[kt][1], qf[qt][1], z);
                st[kt] = z;
            }
            const int* mrp = mbase + ((long)(q0 + qt * 16 + c) << 11) + kv0 + g * 4;
            float p[4][4];
            float s = 0.f;
#pragma unroll
            for (int kt = 0; kt < 4; ++kt) {
                i32x4 mkv = *(const i32x4*)(mrp + kt * 16);
#pragma unroll
                for (int r = 0; r < 4; ++r) {
                    float val = (mkv[r] != 0) ? st[kt][r] : 0.0f;
                    float e = exp2f(val);
                    p[kt][r] = e;
                    s += e;
                }
            }
            lsum[qt] += s;
            short8 pb0, pb1;
            pb0[0] = f2bf(p[0][0]); pb0[1] = f2bf(p[0][1]); pb0[2] = f2bf(p[0][2]); pb0[3] = f2bf(p[0][3]);
            pb0[4] = f2bf(p[1][0]); pb0[5] = f2bf(p[1][1]); pb0[6] = f2bf(p[1][2]); pb0[7] = f2bf(p[1][3]);
            pb1[0] = f2bf(p[2][0]); pb1[1] = f2bf(p[2][1]); pb1[2] = f2bf(p[2][2]); pb1[3] = f2bf(p[2][3]);
            pb1[4] = f2bf(p[3][0]); pb1[5] = f2bf(p[3][1]); pb1[6] = f2bf(p[3][2]); pb1[7] = f2bf(p[3][3]);
#pragma unroll
            for (int dt = 0; dt < 4; ++dt) {
                acc[qt][dt] = MFMA(vf[dt][0], pb0, acc[qt][dt]);
                acc[qt][dt] = MFMA(vf[dt][1], pb1, acc[qt][dt]);
            }
        }
    }
#pragma unroll
    for (int qt = 0; qt < 4; ++qt) {
        float t0 = lsum[qt];
        t0 += __shfl_xor(t0, 16);
        t0 += __shfl_xor(t0, 32);
        float inv = 1.0f / t0;
        float* orow = obase + (long)(q0 + qt * 16 + c) * HD_;
#pragma unroll
        for (int dt = 0; dt < 4; ++dt) {
            f32x4 o = acc[qt][dt] * inv;
            *(f32x4*)(orow + dt * 16 + g * 4) = o;
        }
    }
}

extern "C" void kernel_launch(void* const* d_in, const int* in_sizes, int n_in,
                              void* d_out, int out_size, void* d_ws, size_t ws_size,
                              hipStream_t stream) {
    const float* q = (const float*)d_in[0];
    const float* k = (const float*)d_in[1];
    const float* v = (const float*)d_in[2];
    const int*   m = (const int*)d_in[3];
    float* out = (float*)d_out;

    size_t need = (size_t)2 * KP_ELEMS * sizeof(short);   // 32 MiB
    if (ws_size >= need) {
        short* Kp = (short*)d_ws;
        short* Vp = Kp + KP_ELEMS;
        prepack_k<<<dim3(4096), dim3(256), 0, stream>>>(k, Kp);
        prepack_v<<<dim3(4096), dim3(256), 0, stream>>>(v, Vp);
        attn_fwd2<<<dim3(512), dim3(256), 0, stream>>>(q, Kp, Vp, m, out);
    } else {
        attn_fwd<<<dim3(512), dim3(256), 0, stream>>>(q, k, v, m, out);
    }
}